// Round 2
// baseline (349.589 us; speedup 1.0000x reference)
//
#include <hip/hip_runtime.h>

#define N_SEQ 256
#define T_LEN 1024
#define TP1   (T_LEN + 1)          // 1025
#define J_NUM 24
#define ITEMS (TP1 * J_NUM)        // 24600 items per sequence
#define TOTAL_ITEMS (N_SEQ * ITEMS)          // 6,297,600
#define TOTAL_GROUPS (TOTAL_ITEMS / 4)       // 1,574,400 (4 items per thread)
#define GP_TOTAL (N_SEQ * TP1 * J_NUM * 3)   // global_pos element count

// ---------------------------------------------------------------------------
// Kernel A: per-sequence scans. 1 block per sequence, 1024 threads.
// Writes ws_quat[n*TP1+t] = (w, y) yaw quat, ws_pos[n*TP1+t] = (x, z) displ.
// ---------------------------------------------------------------------------
__device__ __forceinline__ float block_scan_incl(float v, float* wsum, int tid) {
    const int lane = tid & 63;
    const int wid  = tid >> 6;
    #pragma unroll
    for (int off = 1; off < 64; off <<= 1) {
        float u = __shfl_up(v, off, 64);
        if (lane >= off) v += u;
    }
    if (lane == 63) wsum[wid] = v;
    __syncthreads();
    if (tid == 0) {
        float acc = 0.0f;
        #pragma unroll
        for (int i = 0; i < 16; ++i) { float t = wsum[i]; wsum[i] = acc; acc += t; }
    }
    __syncthreads();
    return v + wsum[wid];
}

extern "C" __global__ void __launch_bounds__(1024)
scan_kernel(const float* __restrict__ root_rvel,   // (N, T, 1, 1)
            const float* __restrict__ root_vel,    // (N, T, 1, 2)
            float2* __restrict__ ws_quat,          // (N, T+1) (w, y)
            float2* __restrict__ ws_pos)           // (N, T+1) (x, z)
{
    const int n   = blockIdx.x;
    const int tid = threadIdx.x;

    __shared__ float  r_s[TP1];
    __shared__ float2 quat_s[TP1];
    __shared__ float  ws_a[16], ws_b[16], ws_c[16];

    // scan root_rvel -> cumulative yaw angle
    {
        float v = root_rvel[n * T_LEN + tid];
        float incl = block_scan_incl(v, ws_a, tid);
        if (tid == 0) r_s[0] = 0.0f;
        r_s[tid + 1] = incl;
    }
    __syncthreads();

    // axis-angle (0, r, 0) -> quat (w, y)
    for (int idx = tid; idx < TP1; idx += 1024) {
        float r     = r_s[idx];
        float angle = fabsf(r);
        float half  = 0.5f * angle;
        float k = (angle < 1e-6f) ? (0.5f - angle * angle * (1.0f / 48.0f))
                                  : (__builtin_sinf(half) / angle);
        float2 q = make_float2(__builtin_cosf(half), r * k);
        quat_s[idx] = q;
        ws_quat[n * TP1 + idx] = q;
    }
    __syncthreads();

    // rotate root_vel by quat[t], scan -> displacement (x, z); y is exactly 0
    {
        float2 vel = ((const float2*)root_vel)[n * T_LEN + tid];
        float2 q   = quat_s[tid];
        float  w = q.x, y = q.y;
        float t1x = w * vel.x + y * vel.y;
        float t1z = w * vel.y - y * vel.x;
        float ax  = t1x * w + t1z * y;
        float az  = t1z * w - t1x * y;
        float ix = block_scan_incl(ax, ws_b, tid);
        float iz = block_scan_incl(az, ws_c, tid);
        if (tid == 0) ws_pos[n * TP1] = make_float2(0.0f, 0.0f);
        ws_pos[n * TP1 + tid + 1] = make_float2(ix, iz);
    }
}

// ---------------------------------------------------------------------------
// Kernel B: fully elementwise over all (n, t, j) items, 4 items per thread so
// every global access is an aligned float4. 24 % 4 == 0 -> a 4-item group
// never crosses a timestep boundary (single quat/pos fetch per thread).
// ---------------------------------------------------------------------------
extern "C" __global__ void __launch_bounds__(256)
elem_kernel(const float4* __restrict__ rot4,      // local_rot as float4
            const float4* __restrict__ pos4,      // local_pos as float4
            const float2* __restrict__ ws_quat,   // (N, T+1)
            const float2* __restrict__ ws_pos,    // (N, T+1)
            float4* __restrict__ out_rot4,        // out_rot as float4
            float4* __restrict__ out_pos4)        // out_pos as float4
{
    const unsigned g = blockIdx.x * 256u + threadIdx.x;   // group index
    if (g >= TOTAL_GROUPS) return;
    const unsigned base = g * 4u;                         // first item
    const unsigned seq  = base / ITEMS;
    const unsigned t    = (base - seq * ITEMS) / J_NUM;

    const float2 qt = ws_quat[seq * TP1 + t];
    const float2 ps = ws_pos [seq * TP1 + t];
    const float w = qt.x, yq = qt.y;
    const float wwyy = w * w + yq * yq;

    // load 4 items of local_rot (24 floats) and local_pos (12 floats)
    float rf[24], pf[12], opf[12];
    {
        const float4* rp = rot4 + (size_t)g * 6;
        #pragma unroll
        for (int i = 0; i < 6; ++i) {
            float4 a = rp[i];
            rf[4*i+0] = a.x; rf[4*i+1] = a.y; rf[4*i+2] = a.z; rf[4*i+3] = a.w;
        }
        const float4* pp = pos4 + (size_t)g * 3;
        #pragma unroll
        for (int i = 0; i < 3; ++i) {
            float4 a = pp[i];
            pf[4*i+0] = a.x; pf[4*i+1] = a.y; pf[4*i+2] = a.z; pf[4*i+3] = a.w;
        }
    }

    float4* orp = out_rot4 + (size_t)g * 4;

    #pragma unroll
    for (int k = 0; k < 4; ++k) {
        float a1x = rf[6*k+0], a1y = rf[6*k+1], a1z = rf[6*k+2];
        float a2x = rf[6*k+3], a2y = rf[6*k+4], a2z = rf[6*k+5];

        float inv1 = 1.0f / sqrtf(a1x * a1x + a1y * a1y + a1z * a1z);
        float b1x = a1x * inv1, b1y = a1y * inv1, b1z = a1z * inv1;
        float dp  = b1x * a2x + b1y * a2y + b1z * a2z;
        float px  = a2x - dp * b1x, py = a2y - dp * b1y, pz = a2z - dp * b1z;
        float inv2 = 1.0f / sqrtf(px * px + py * py + pz * pz);
        float b2x = px * inv2, b2y = py * inv2, b2z = pz * inv2;
        float b3x = b1y * b2z - b1z * b2y;
        float b3y = b1z * b2x - b1x * b2z;
        float b3z = b1x * b2y - b1y * b2x;

        float m00 = b1x, m01 = b1y, m02 = b1z;
        float m10 = b2x, m11 = b2y, m12 = b2z;
        float m20 = b3x, m21 = b3y, m22 = b3z;

        float qa0 = sqrtf(fmaxf(1.0f + m00 + m11 + m22, 0.0f));
        float qa1 = sqrtf(fmaxf(1.0f + m00 - m11 - m22, 0.0f));
        float qa2 = sqrtf(fmaxf(1.0f - m00 + m11 - m22, 0.0f));
        float qa3 = sqrtf(fmaxf(1.0f - m00 - m11 + m22, 0.0f));

        int best = 0; float bv = qa0;
        if (qa1 > bv) { best = 1; bv = qa1; }
        if (qa2 > bv) { best = 2; bv = qa2; }
        if (qa3 > bv) { best = 3; bv = qa3; }

        float lw, lx, ly, lz;
        if (best == 0)      { lw = qa0 * qa0;  lx = m21 - m12;  ly = m02 - m20;  lz = m10 - m01; }
        else if (best == 1) { lw = m21 - m12;  lx = qa1 * qa1;  ly = m10 + m01;  lz = m02 + m20; }
        else if (best == 2) { lw = m02 - m20;  lx = m10 + m01;  ly = qa2 * qa2;  lz = m21 + m12; }
        else                { lw = m10 - m01;  lx = m20 + m02;  ly = m21 + m12;  lz = qa3 * qa3; }
        float invd = 1.0f / (2.0f * fmaxf(bv, 0.1f));
        lw *= invd; lx *= invd; ly *= invd; lz *= invd;

        // compose with yaw quat (w, 0, y, 0), standardize
        float ow = w * lw - yq * ly;
        float ox = w * lx + yq * lz;
        float oy = w * ly + yq * lw;
        float oz = w * lz - yq * lx;
        if (ow < 0.0f) { ow = -ow; ox = -ox; oy = -oy; oz = -oz; }
        orp[k] = make_float4(ow, ox, oy, oz);

        // rotate local_pos, add root displacement
        float vx = pf[3*k+0], vy = pf[3*k+1], vz = pf[3*k+2];
        float t1x = w * vx + yq * vz;
        float t1z = w * vz - yq * vx;
        opf[3*k+0] = t1x * w + t1z * yq + ps.x;
        opf[3*k+1] = wwyy * vy;
        opf[3*k+2] = t1z * w - t1x * yq + ps.y;
    }

    float4* opp = out_pos4 + (size_t)g * 3;
    #pragma unroll
    for (int i = 0; i < 3; ++i)
        opp[i] = make_float4(opf[4*i+0], opf[4*i+1], opf[4*i+2], opf[4*i+3]);
}

extern "C" void kernel_launch(void* const* d_in, const int* in_sizes, int n_in,
                              void* d_out, int out_size, void* d_ws, size_t ws_size,
                              hipStream_t stream) {
    (void)in_sizes; (void)n_in; (void)ws_size; (void)out_size;
    const float* root_rvel = (const float*)d_in[0];
    const float* local_pos = (const float*)d_in[1];
    const float* local_rot = (const float*)d_in[2];
    const float* root_vel  = (const float*)d_in[3];
    float* out = (float*)d_out;

    float2* ws_quat = (float2*)d_ws;                       // N*TP1 float2
    float2* ws_pos  = ws_quat + (size_t)N_SEQ * TP1;       // N*TP1 float2

    scan_kernel<<<N_SEQ, 1024, 0, stream>>>(root_rvel, root_vel, ws_quat, ws_pos);

    elem_kernel<<<TOTAL_GROUPS / 256, 256, 0, stream>>>(
        (const float4*)local_rot, (const float4*)local_pos,
        ws_quat, ws_pos,
        (float4*)(out + GP_TOTAL),   // out_rot
        (float4*)out);               // out_pos
}

// Round 3
// 334.707 us; speedup vs baseline: 1.0445x; 1.0445x over previous
//
#include <hip/hip_runtime.h>

#define N_SEQ 256
#define T_LEN 1024
#define TP1   (T_LEN + 1)          // 1025
#define J_NUM 24
#define SEQ_ITEMS (TP1 * J_NUM)    // 24600 items per sequence
#define TOTAL_ITEMS (N_SEQ * SEQ_ITEMS)      // 6,297,600
#define GP_TOTAL (N_SEQ * TP1 * J_NUM * 3)   // global_pos element count
#define NBLOCKS (TOTAL_ITEMS / 256)          // 24600 blocks, 256 items each

// ---------------------------------------------------------------------------
// Kernel A: per-sequence scans. 1 block per sequence, 1024 threads.
// Writes ws4[n*TP1+t] = (w, y, pos_x, pos_z).
// ---------------------------------------------------------------------------
__device__ __forceinline__ float block_scan_incl(float v, float* wsum, int tid) {
    const int lane = tid & 63;
    const int wid  = tid >> 6;
    #pragma unroll
    for (int off = 1; off < 64; off <<= 1) {
        float u = __shfl_up(v, off, 64);
        if (lane >= off) v += u;
    }
    if (lane == 63) wsum[wid] = v;
    __syncthreads();
    if (tid == 0) {
        float acc = 0.0f;
        #pragma unroll
        for (int i = 0; i < 16; ++i) { float t = wsum[i]; wsum[i] = acc; acc += t; }
    }
    __syncthreads();
    return v + wsum[wid];
}

extern "C" __global__ void __launch_bounds__(1024)
scan_kernel(const float* __restrict__ root_rvel,   // (N, T, 1, 1)
            const float* __restrict__ root_vel,    // (N, T, 1, 2)
            float4* __restrict__ ws4)              // (N, T+1) (w, y, px, pz)
{
    const int n   = blockIdx.x;
    const int tid = threadIdx.x;

    __shared__ float  r_s[TP1];
    __shared__ float2 quat_s[TP1];
    __shared__ float  ws_a[16], ws_b[16], ws_c[16];

    // scan root_rvel -> cumulative yaw angle
    {
        float v = root_rvel[n * T_LEN + tid];
        float incl = block_scan_incl(v, ws_a, tid);
        if (tid == 0) r_s[0] = 0.0f;
        r_s[tid + 1] = incl;
    }
    __syncthreads();

    // axis-angle (0, r, 0) -> quat (w, y)
    for (int idx = tid; idx < TP1; idx += 1024) {
        float r     = r_s[idx];
        float angle = fabsf(r);
        float half  = 0.5f * angle;
        float k = (angle < 1e-6f) ? (0.5f - angle * angle * (1.0f / 48.0f))
                                  : (__builtin_sinf(half) / angle);
        quat_s[idx] = make_float2(__builtin_cosf(half), r * k);
    }
    __syncthreads();

    // rotate root_vel by quat[t], scan -> displacement (x, z); y is exactly 0
    {
        float2 vel = ((const float2*)root_vel)[n * T_LEN + tid];
        float2 q   = quat_s[tid];
        float  w = q.x, y = q.y;
        float t1x = w * vel.x + y * vel.y;
        float t1z = w * vel.y - y * vel.x;
        float ax  = t1x * w + t1z * y;
        float az  = t1z * w - t1x * y;
        float ix = block_scan_incl(ax, ws_b, tid);
        float iz = block_scan_incl(az, ws_c, tid);
        float2 qn = quat_s[tid + 1];
        ws4[n * TP1 + tid + 1] = make_float4(qn.x, qn.y, ix, iz);
        if (tid == 0) ws4[n * TP1] = make_float4(1.0f, 0.0f, 0.0f, 0.0f);
    }
}

// ---------------------------------------------------------------------------
// Kernel B: 1 item per thread, 256 items per block, LDS-staged so every
// global access is a lane-contiguous float4.
//   s_rot: 256 items x 6 floats, padded stride 7 (gcd(7,32)=1 -> no conflicts)
//   s_pos: 256 items x 3 floats, padded stride 5
//   s_out: 256 items x 3 floats, tight (stride 3, odd -> no conflicts)
// ---------------------------------------------------------------------------
extern "C" __global__ void __launch_bounds__(256)
elem_kernel(const float4* __restrict__ rot4,      // local_rot as float4
            const float4* __restrict__ pos4,      // local_pos as float4
            const float4* __restrict__ ws4,       // (N, T+1)
            float4* __restrict__ out_rot4,        // out_rot as float4
            float4* __restrict__ out_pos4)        // out_pos as float4
{
    __shared__ float  s_rot[256 * 7];   // 7168 B
    __shared__ float  s_pos[256 * 5];   // 5120 B
    __shared__ float4 s_out4[192];      // 3072 B (768 floats, 16B-aligned)
    float* s_out = (float*)s_out4;

    const int tid = threadIdx.x;
    const unsigned blk = blockIdx.x;

    // ---- stage local_rot: 384 float4 per block, coalesced ----
    {
        const float4* rbase = rot4 + (size_t)blk * 384;
        #pragma unroll
        for (int it = 0; it < 2; ++it) {
            int q = tid + it * 256;
            if (q < 384) {
                float4 v = rbase[q];
                int f = 4 * q;
                float vv[4] = {v.x, v.y, v.z, v.w};
                #pragma unroll
                for (int m = 0; m < 4; ++m) {
                    int ff = f + m;
                    s_rot[7 * (ff / 6) + (ff % 6)] = vv[m];
                }
            }
        }
    }
    // ---- stage local_pos: 192 float4 per block, coalesced ----
    if (tid < 192) {
        float4 v = (pos4 + (size_t)blk * 192)[tid];
        int f = 4 * tid;
        float vv[4] = {v.x, v.y, v.z, v.w};
        #pragma unroll
        for (int m = 0; m < 4; ++m) {
            int ff = f + m;
            s_pos[5 * (ff / 3) + (ff % 3)] = vv[m];
        }
    }
    __syncthreads();

    // ---- per-item compute ----
    const unsigned a   = blk * 256u + (unsigned)tid;   // absolute item
    const unsigned seq = a / (unsigned)SEQ_ITEMS;
    const unsigned rem = a - seq * (unsigned)SEQ_ITEMS;
    const unsigned t   = rem / (unsigned)J_NUM;

    const float4 wq = ws4[seq * (unsigned)TP1 + t];
    const float w = wq.x, yq = wq.y;

    const int rb = 7 * tid;
    float a1x = s_rot[rb + 0], a1y = s_rot[rb + 1], a1z = s_rot[rb + 2];
    float a2x = s_rot[rb + 3], a2y = s_rot[rb + 4], a2z = s_rot[rb + 5];

    float inv1 = __builtin_amdgcn_rsqf(a1x * a1x + a1y * a1y + a1z * a1z);
    float b1x = a1x * inv1, b1y = a1y * inv1, b1z = a1z * inv1;
    float dp  = b1x * a2x + b1y * a2y + b1z * a2z;
    float px  = a2x - dp * b1x, py = a2y - dp * b1y, pz = a2z - dp * b1z;
    float inv2 = __builtin_amdgcn_rsqf(px * px + py * py + pz * pz);
    float b2x = px * inv2, b2y = py * inv2, b2z = pz * inv2;
    float b3x = b1y * b2z - b1z * b2y;
    float b3y = b1z * b2x - b1x * b2z;
    float b3z = b1x * b2y - b1y * b2x;

    float m00 = b1x, m01 = b1y, m02 = b1z;
    float m10 = b2x, m11 = b2y, m12 = b2z;
    float m20 = b3x, m21 = b3y, m22 = b3z;

    // squared q_abs (relu'd); argmax on squares == argmax on q_abs
    float s0 = fmaxf(1.0f + m00 + m11 + m22, 0.0f);
    float s1 = fmaxf(1.0f + m00 - m11 - m22, 0.0f);
    float s2 = fmaxf(1.0f - m00 + m11 - m22, 0.0f);
    float s3 = fmaxf(1.0f - m00 - m11 + m22, 0.0f);

    int best = 0; float bs = s0;
    if (s1 > bs) { best = 1; bs = s1; }
    if (s2 > bs) { best = 2; bs = s2; }
    if (s3 > bs) { best = 3; bs = s3; }

    float lw, lx, ly, lz;
    if (best == 0)      { lw = bs;         lx = m21 - m12;  ly = m02 - m20;  lz = m10 - m01; }
    else if (best == 1) { lw = m21 - m12;  lx = bs;         ly = m10 + m01;  lz = m02 + m20; }
    else if (best == 2) { lw = m02 - m20;  lx = m10 + m01;  ly = bs;         lz = m21 + m12; }
    else                { lw = m10 - m01;  lx = m20 + m02;  ly = m21 + m12;  lz = bs;        }

    float bv   = __builtin_amdgcn_sqrtf(bs);
    float invd = __builtin_amdgcn_rcpf(2.0f * fmaxf(bv, 0.1f));
    lw *= invd; lx *= invd; ly *= invd; lz *= invd;

    // compose with yaw quat (w, 0, y, 0), standardize
    float ow = w * lw - yq * ly;
    float ox = w * lx + yq * lz;
    float oy = w * ly + yq * lw;
    float oz = w * lz - yq * lx;
    if (ow < 0.0f) { ow = -ow; ox = -ox; oy = -oy; oz = -oz; }
    out_rot4[a] = make_float4(ow, ox, oy, oz);   // coalesced: 1 float4/item

    // rotate local_pos, add root displacement
    const int pb = 5 * tid;
    float vx = s_pos[pb + 0], vy = s_pos[pb + 1], vz = s_pos[pb + 2];
    float t1x = w * vx + yq * vz;
    float t1z = w * vz - yq * vx;
    s_out[3 * tid + 0] = t1x * w + t1z * yq + wq.z;
    s_out[3 * tid + 1] = (w * w + yq * yq) * vy;
    s_out[3 * tid + 2] = t1z * w - t1x * yq + wq.w;
    __syncthreads();

    // ---- drain out_pos staging: 192 float4 per block, coalesced ----
    if (tid < 192) {
        out_pos4[(size_t)blk * 192 + tid] = s_out4[tid];
    }
}

extern "C" void kernel_launch(void* const* d_in, const int* in_sizes, int n_in,
                              void* d_out, int out_size, void* d_ws, size_t ws_size,
                              hipStream_t stream) {
    (void)in_sizes; (void)n_in; (void)ws_size; (void)out_size;
    const float* root_rvel = (const float*)d_in[0];
    const float* local_pos = (const float*)d_in[1];
    const float* local_rot = (const float*)d_in[2];
    const float* root_vel  = (const float*)d_in[3];
    float* out = (float*)d_out;

    float4* ws4 = (float4*)d_ws;   // N*TP1 float4 = 4.2 MB

    scan_kernel<<<N_SEQ, 1024, 0, stream>>>(root_rvel, root_vel, ws4);

    elem_kernel<<<NBLOCKS, 256, 0, stream>>>(
        (const float4*)local_rot, (const float4*)local_pos, ws4,
        (float4*)(out + GP_TOTAL),   // out_rot
        (float4*)out);               // out_pos
}